// Round 1
// baseline (1683.973 us; speedup 1.0000x reference)
//
#include <hip/hip_runtime.h>

#define Bsz 1024
#define Tt 200
#define Hh 128
#define Gg 384
#define OUT0_SZ (1024L*199*128)

#define WSEG 49152              // frag elements per gate matrix (384*128)
#define WTOT (4*WSEG + 16384)   // + h2o (128*128)

typedef _Float16 half8 __attribute__((ext_vector_type(8)));
typedef float floatx4 __attribute__((ext_vector_type(4)));

// Pack fp32 weights into fp16 MFMA B-fragment order:
// idx = ((tile*4 + kstep)*64 + lane)*8 + j  ->  W[tile*16 + (lane&15)][kstep*32 + (lane>>4)*8 + j]
__global__ void pack_weights(const float* __restrict__ Wih, const float* __restrict__ Whh,
                             const float* __restrict__ h2o_w, ushort* __restrict__ wbuf) {
    int idx = blockIdx.x * blockDim.x + threadIdx.x;
    if (idx >= WTOT) return;
    const float* src; int off;
    if      (idx <   WSEG) { src = Wih;            off = idx;          }
    else if (idx < 2*WSEG) { src = Whh;            off = idx -   WSEG; }
    else if (idx < 3*WSEG) { src = Wih + Gg*Hh;    off = idx - 2*WSEG; }
    else if (idx < 4*WSEG) { src = Whh + Gg*Hh;    off = idx - 3*WSEG; }
    else                   { src = h2o_w;          off = idx - 4*WSEG; }
    int j    = off & 7;
    int lane = (off >> 3) & 63;
    int kt   = (off >> 9) & 3;
    int tile = off >> 11;
    int n = tile*16 + (lane & 15);
    int k = kt*32 + (lane >> 4)*8 + j;
    union { _Float16 h; ushort u; } cv;
    cv.h = (_Float16)src[n*Hh + k];
    wbuf[idx] = cv.u;
}

// blocks 0..63: GRU over 16 batch rows each, all 200 steps.
// blocks 64..255: gather/copy of out1, out2, out3-first-half.
__global__ __launch_bounds__(512) void gru_fused(
    const int* __restrict__ il, const float* __restrict__ mask,
    const int* __restrict__ negl, const float* __restrict__ emb,
    const float* __restrict__ bih, const float* __restrict__ bhh,
    const float* __restrict__ h2o_b, const ushort* __restrict__ wbuf,
    float* __restrict__ out)
{
    __shared__ _Float16 x_lds[16*136];   // layer0 input, later h2o input (136: pad for conflict-free b128)
    __shared__ _Float16 x1_lds[16*136];  // layer1 input (h0 pre-mask)
    __shared__ _Float16 h0_lds[16*136];  // masked state L0
    __shared__ _Float16 h1_lds[16*136];  // masked state L1
    __shared__ float    g_lds[16*516];   // gates: [b][n] n<128:r 128..255:z 256..383:inn 384..511:hn
    __shared__ float    brz_s[2*256];    // bih+bhh for r,z per layer
    __shared__ float    bin_s[2*128];
    __shared__ float    bhn_s[2*128];
    __shared__ float    bo_s[128];
    __shared__ float    keep_s[16];

    const int tid = threadIdx.x;
    float* out0 = out;
    float* out1 = out + OUT0_SZ;
    float* out2 = out + 2*OUT0_SZ;
    float* out3 = out + 3*OUT0_SZ;

    if (blockIdx.x >= 64) {
        // ---------------- copy path ----------------
        const float4* emb4 = (const float4*)emb;
        float4* o1 = (float4*)out1;
        float4* o2 = (float4*)out2;
        float4* o3 = (float4*)out3;
        const int nA = 1024*200*32;      // out3 first half, float4 tasks
        const int nB = 1024*199*32;      // out1 / out2
        const int total = nA + 2*nB;
        const int stride = 192*512;
        for (int i = (blockIdx.x - 64)*512 + tid; i < total; i += stride) {
            if (i < nA) {
                int c = i & 31; int bt = i >> 5;
                int e = il[bt];
                o3[bt*64 + c] = emb4[(long)e*32 + c];           // row=256 floats, first half
            } else if (i < nA + nB) {
                int ii = i - nA; int c = ii & 31; int bt = ii >> 5;
                int b = bt / 199, t = bt - b*199;
                int e = il[b*Tt + t + 1];
                o1[bt*32 + c] = emb4[(long)e*32 + c];
            } else {
                int ii = i - nA - nB; int c = ii & 31; int bt = ii >> 5;
                int b = bt / 199, t = bt - b*199;
                int e = negl[b*Tt + t];
                o2[bt*32 + c] = emb4[(long)e*32 + c];
            }
        }
        return;
    }

    // ---------------- GRU path ----------------
    const int wave = tid >> 6;
    const int lane = tid & 63;
    const int b0   = blockIdx.x * 16;
    const int col  = lane & 15;
    const int q    = lane >> 4;
    const int arow = (lane & 15)*136;    // A-frag row base
    const int koffq = (lane >> 4)*8;

    // biases -> LDS (r,z combined; n-gate kept separate)
    if (tid < 512) { int l = tid >> 8, n = tid & 255; brz_s[tid] = bih[l*Gg + n] + bhh[l*Gg + n]; }
    if (tid < 256) { int l = tid >> 7, jj = tid & 127; bin_s[tid] = bih[l*Gg + 256 + jj]; bhn_s[tid] = bhh[l*Gg + 256 + jj]; }
    if (tid < 128) bo_s[tid] = h2o_b[tid];
    for (int i = tid; i < 16*136; i += 512) { h0_lds[i] = (_Float16)0.f; h1_lds[i] = (_Float16)0.f; }

    // persistent register weights: layer0 (wave w owns gate tiles w, 8+w, 16+w)
    const half8* wb = (const half8*)wbuf;
    half8 wih0[3][4], whh0[3][4];
#pragma unroll
    for (int s = 0; s < 3; s++) {
        const int tl = (s == 0) ? wave : (s == 1) ? (8 + wave) : (16 + wave);
#pragma unroll
        for (int k = 0; k < 4; k++) {
            wih0[s][k] = wb[0*6144 + (tl*4 + k)*64 + lane];
            whh0[s][k] = wb[1*6144 + (tl*4 + k)*64 + lane];
        }
    }

    for (int t = 0; t < Tt; t++) {
        // ---- Phase X: gather embeddings -> x_lds (fp16) ----
        {
            int r = tid >> 5, c4 = tid & 31;
            int e = il[(b0 + r)*Tt + t];
            float4 v = ((const float4*)emb)[(long)e*32 + c4];
            _Float16* dst = &x_lds[r*136 + c4*4];
            dst[0] = (_Float16)v.x; dst[1] = (_Float16)v.y;
            dst[2] = (_Float16)v.z; dst[3] = (_Float16)v.w;
            if (tid < 16) keep_s[tid] = (mask[(b0 + tid)*Tt + t] != 0.f) ? 1.f : 0.f;
        }
        __syncthreads();

        half8 p_w1r[4], p_w1z[4], p_w1n[4], p_whr[4], p_whz[4], p_whn[4];
        // ---- L0 MFMA ----
        {
            floatx4 acc_r = {0.f,0.f,0.f,0.f}, acc_z = {0.f,0.f,0.f,0.f};
            floatx4 acc_in = {0.f,0.f,0.f,0.f}, acc_hn = {0.f,0.f,0.f,0.f};
#pragma unroll
            for (int k = 0; k < 4; k++) {
                half8 xf = *(const half8*)&x_lds[arow + k*32 + koffq];
                half8 hf = *(const half8*)&h0_lds[arow + k*32 + koffq];
                acc_r  = __builtin_amdgcn_mfma_f32_16x16x32_f16(xf, wih0[0][k], acc_r, 0, 0, 0);
                acc_r  = __builtin_amdgcn_mfma_f32_16x16x32_f16(hf, whh0[0][k], acc_r, 0, 0, 0);
                acc_z  = __builtin_amdgcn_mfma_f32_16x16x32_f16(xf, wih0[1][k], acc_z, 0, 0, 0);
                acc_z  = __builtin_amdgcn_mfma_f32_16x16x32_f16(hf, whh0[1][k], acc_z, 0, 0, 0);
                acc_in = __builtin_amdgcn_mfma_f32_16x16x32_f16(xf, wih0[2][k], acc_in, 0, 0, 0);
                acc_hn = __builtin_amdgcn_mfma_f32_16x16x32_f16(hf, whh0[2][k], acc_hn, 0, 0, 0);
            }
#pragma unroll
            for (int r2 = 0; r2 < 4; r2++) {
                int row = q*4 + r2;
                g_lds[row*516 +       wave*16 + col] = acc_r[r2];
                g_lds[row*516 + 128 + wave*16 + col] = acc_z[r2];
                g_lds[row*516 + 256 + wave*16 + col] = acc_in[r2];
                g_lds[row*516 + 384 + wave*16 + col] = acc_hn[r2];
            }
            // prefetch layer1 weight fragments from L2 (used after 2 barriers -> latency hidden)
#pragma unroll
            for (int k = 0; k < 4; k++) {
                p_w1r[k] = wb[2*6144 + (( 0 + wave)*4 + k)*64 + lane];
                p_w1z[k] = wb[2*6144 + (( 8 + wave)*4 + k)*64 + lane];
                p_w1n[k] = wb[2*6144 + ((16 + wave)*4 + k)*64 + lane];
                p_whr[k] = wb[3*6144 + (( 0 + wave)*4 + k)*64 + lane];
                p_whz[k] = wb[3*6144 + (( 8 + wave)*4 + k)*64 + lane];
                p_whn[k] = wb[3*6144 + ((16 + wave)*4 + k)*64 + lane];
            }
        }
        __syncthreads();

        // ---- L0 elementwise: gates -> h0new; x1_lds=pre-mask, h0_lds=masked ----
        {
            int jj = tid & 127, bq = tid >> 7;
#pragma unroll
            for (int itr = 0; itr < 4; itr++) {
                int b = itr*4 + bq;
                float gr  = g_lds[b*516 +       jj] + brz_s[jj];
                float gz  = g_lds[b*516 + 128 + jj] + brz_s[128 + jj];
                float gin = g_lds[b*516 + 256 + jj] + bin_s[jj];
                float ghn = g_lds[b*516 + 384 + jj] + bhn_s[jj];
                float rr = 1.f/(1.f + __expf(-gr));
                float zz = 1.f/(1.f + __expf(-gz));
                float nn = tanhf(gin + rr*ghn);
                float hp = (float)h0_lds[b*136 + jj];
                float hv = (1.f - zz)*nn + zz*hp;
                x1_lds[b*136 + jj] = (_Float16)hv;
                h0_lds[b*136 + jj] = (_Float16)(hv * keep_s[b]);
            }
        }
        __syncthreads();

        half8 p_o[4];
        // ---- L1 MFMA (streamed weights) ----
        {
            floatx4 acc_r = {0.f,0.f,0.f,0.f}, acc_z = {0.f,0.f,0.f,0.f};
            floatx4 acc_in = {0.f,0.f,0.f,0.f}, acc_hn = {0.f,0.f,0.f,0.f};
#pragma unroll
            for (int k = 0; k < 4; k++) {
                half8 xf = *(const half8*)&x1_lds[arow + k*32 + koffq];
                half8 hf = *(const half8*)&h1_lds[arow + k*32 + koffq];
                acc_r  = __builtin_amdgcn_mfma_f32_16x16x32_f16(xf, p_w1r[k], acc_r, 0, 0, 0);
                acc_r  = __builtin_amdgcn_mfma_f32_16x16x32_f16(hf, p_whr[k], acc_r, 0, 0, 0);
                acc_z  = __builtin_amdgcn_mfma_f32_16x16x32_f16(xf, p_w1z[k], acc_z, 0, 0, 0);
                acc_z  = __builtin_amdgcn_mfma_f32_16x16x32_f16(hf, p_whz[k], acc_z, 0, 0, 0);
                acc_in = __builtin_amdgcn_mfma_f32_16x16x32_f16(xf, p_w1n[k], acc_in, 0, 0, 0);
                acc_hn = __builtin_amdgcn_mfma_f32_16x16x32_f16(hf, p_whn[k], acc_hn, 0, 0, 0);
            }
#pragma unroll
            for (int r2 = 0; r2 < 4; r2++) {
                int row = q*4 + r2;
                g_lds[row*516 +       wave*16 + col] = acc_r[r2];
                g_lds[row*516 + 128 + wave*16 + col] = acc_z[r2];
                g_lds[row*516 + 256 + wave*16 + col] = acc_in[r2];
                g_lds[row*516 + 384 + wave*16 + col] = acc_hn[r2];
            }
            // prefetch h2o fragments
#pragma unroll
            for (int k = 0; k < 4; k++) p_o[k] = wb[4*6144 + (wave*4 + k)*64 + lane];
        }
        __syncthreads();

        // ---- L1 elementwise: h1new; x_lds=pre-mask (h2o input), h1_lds=masked ----
        {
            int jj = tid & 127, bq = tid >> 7;
#pragma unroll
            for (int itr = 0; itr < 4; itr++) {
                int b = itr*4 + bq;
                float gr  = g_lds[b*516 +       jj] + brz_s[256 + jj];
                float gz  = g_lds[b*516 + 128 + jj] + brz_s[256 + 128 + jj];
                float gin = g_lds[b*516 + 256 + jj] + bin_s[128 + jj];
                float ghn = g_lds[b*516 + 384 + jj] + bhn_s[128 + jj];
                float rr = 1.f/(1.f + __expf(-gr));
                float zz = 1.f/(1.f + __expf(-gz));
                float nn = tanhf(gin + rr*ghn);
                float hp = (float)h1_lds[b*136 + jj];
                float hv = (1.f - zz)*nn + zz*hp;
                x_lds[b*136 + jj]  = (_Float16)hv;
                h1_lds[b*136 + jj] = (_Float16)(hv * keep_s[b]);
            }
        }
        __syncthreads();

        // ---- h2o: out = tanh(h1new @ h2o_w^T + b); write out3 (and out0 for t<199) ----
        {
            floatx4 acc_o = {0.f,0.f,0.f,0.f};
#pragma unroll
            for (int k = 0; k < 4; k++) {
                half8 xf = *(const half8*)&x_lds[arow + k*32 + koffq];
                acc_o = __builtin_amdgcn_mfma_f32_16x16x32_f16(xf, p_o[k], acc_o, 0, 0, 0);
            }
            int nout = wave*16 + col;
            float bs = bo_s[nout];
#pragma unroll
            for (int r2 = 0; r2 < 4; r2++) {
                int brow = q*4 + r2;
                float v = tanhf(acc_o[r2] + bs);
                out3[((long)(b0 + brow)*Tt + t)*256 + 128 + nout] = v;
                if (t < Tt - 1) out0[((long)(b0 + brow)*199 + t)*128 + nout] = v;
            }
        }
        __syncthreads();   // protect x_lds before next step's Phase X
    }
}

extern "C" void kernel_launch(void* const* d_in, const int* in_sizes, int n_in,
                              void* d_out, int out_size, void* d_ws, size_t ws_size,
                              hipStream_t stream) {
    const int*   il    = (const int*)  d_in[0];
    const float* msk   = (const float*)d_in[1];
    const int*   negl  = (const int*)  d_in[2];
    const float* emb   = (const float*)d_in[3];
    const float* Wih   = (const float*)d_in[4];
    const float* Whh   = (const float*)d_in[5];
    const float* bih   = (const float*)d_in[6];
    const float* bhh   = (const float*)d_in[7];
    const float* h2o_w = (const float*)d_in[8];
    const float* h2o_b = (const float*)d_in[9];
    float* out = (float*)d_out;
    ushort* wbuf = (ushort*)d_ws;

    pack_weights<<<(WTOT + 255)/256, 256, 0, stream>>>(Wih, Whh, h2o_w, wbuf);
    gru_fused<<<256, 512, 0, stream>>>(il, msk, negl, emb, bih, bhh, h2o_b, wbuf, out);
}